// Round 4
// baseline (2702.175 us; speedup 1.0000x reference)
//
#include <hip/hip_runtime.h>

#define NUM_USER   50000
#define NUM_ITEM   50000
#define NUM_NODES  100000
#define DIM_LATENT 256
#define DIM_ID     64
#define NUM_EDGES  2000000
#define NBUCKET    391        // ceil(100000/256)

typedef __attribute__((ext_vector_type(8))) short bf8_t;
typedef __attribute__((ext_vector_type(4))) float f4_t;

static __device__ __forceinline__ float lrelu(float x) {
    return x > 0.0f ? x : 0.01f * x;
}
static __device__ __forceinline__ unsigned short f2bf(float f) {
    unsigned u = __float_as_uint(f);
    u += 0x7fff + ((u >> 16) & 1);
    return (unsigned short)(u >> 16);
}
static __device__ __forceinline__ float bf2f(unsigned short u) {
    return __uint_as_float(((unsigned)u) << 16);
}

// ---------------- per-node degree ----------------
__global__ void k_count(const int* __restrict__ row, int* __restrict__ cnt) {
    int t = blockIdx.x * blockDim.x + threadIdx.x;
    if (t < NUM_EDGES) atomicAdd(&cnt[row[t]], 1);
}

// ---------------- bucket counts (256 nodes/bucket) + dis ----------------
__global__ void __launch_bounds__(256) k_bcnt(const int* __restrict__ cnt,
                                              int* __restrict__ bcnt,
                                              float* __restrict__ dis) {
    int b = blockIdx.x;
    int t = threadIdx.x;
    int idx = (b << 8) + t;
    int c = (idx < NUM_NODES) ? cnt[idx] : 0;
    if (idx < NUM_NODES) dis[idx] = rsqrtf((float)max(c, 1));
    #pragma unroll
    for (int off = 32; off >= 1; off >>= 1) c += __shfl_xor(c, off);
    __shared__ int ws[4];
    if ((t & 63) == 0) ws[t >> 6] = c;
    __syncthreads();
    if (t == 0) bcnt[b] = ws[0] + ws[1] + ws[2] + ws[3];
}

// ---------------- exclusive scan over 391 bucket counts ----------------
__global__ void __launch_bounds__(512) k_bscan(const int* __restrict__ bcnt,
                                               int* __restrict__ boff,
                                               int* __restrict__ bcursor) {
    __shared__ int wsum[8];
    int t = threadIdx.x;
    int lane = t & 63, w = t >> 6;
    int c = (t < NBUCKET) ? bcnt[t] : 0;
    int v = c;
    #pragma unroll
    for (int off = 1; off < 64; off <<= 1) {
        int u = __shfl_up(v, off);
        if (lane >= off) v += u;
    }
    if (lane == 63) wsum[w] = v;
    __syncthreads();
    int add = 0;
    #pragma unroll
    for (int i = 0; i < 8; ++i) if (i < w) add += wsum[i];
    int ex = v + add - c;
    if (t < NBUCKET) { boff[t] = ex; bcursor[t] = ex; }
    if (t == NBUCKET - 1) boff[NBUCKET] = ex + c;   // == NUM_EDGES
}

// ---------------- bin edges into coarse buckets ----------------
__global__ void k_bin(const int* __restrict__ row, const int* __restrict__ col,
                      int* __restrict__ bcursor, uint2* __restrict__ epair) {
    int t = blockIdx.x * blockDim.x + threadIdx.x;
    if (t < NUM_EDGES) {
        int r = row[t];
        int pos = atomicAdd(&bcursor[r >> 8], 1);
        epair[pos] = make_uint2((unsigned)r, (unsigned)col[t]);
    }
}

// ---------------- weight prep: Wg0,lw0 -> bf16 fragment-order table ----------------
__global__ void __launch_bounds__(256) k_wprep(const float* __restrict__ Wg,
                                               const float* __restrict__ Wl,
                                               unsigned short* __restrict__ wfrag) {
    int g = blockIdx.x * 256 + threadIdx.x;     // 4096 total
    if (g >= 4096) return;
    int ks = g >> 9;
    int t  = (g >> 6) & 7;
    int l  = g & 63;
    const float* W = (t < 4) ? Wg : Wl;
    int colg = (t & 3) * 16 + (l & 15);
    int kb = ks * 32 + (l >> 4) * 8;
    unsigned short o[8];
    #pragma unroll
    for (int e = 0; e < 8; ++e) o[e] = f2bf(W[(size_t)(kb + e) * DIM_ID + colg]);
    unsigned short* dst = wfrag + (size_t)g * 8;
    #pragma unroll
    for (int e = 0; e < 8; ++e) dst[e] = o[e];
}

// ---------------- layer 1 (MFMA) ----------------
__global__ void __launch_bounds__(256) k_l1(
    const float* __restrict__ pref, const float* __restrict__ feat,
    const unsigned short* __restrict__ wfrag,
    const float* __restrict__ lb,   const float* __restrict__ idemb,
    const float* __restrict__ dis,
    unsigned short* __restrict__ hbf, unsigned short* __restrict__ xhat)
{
    __shared__ unsigned short xs[64][264];
    const int w = threadIdx.x >> 6;
    const int lane = threadIdx.x & 63;
    const int ql = lane & 15, q = lane >> 4;
    const int rowBase = blockIdx.x * 64;

    for (int r = 0; r < 16; ++r) {
        int n = rowBase + w * 16 + r;
        float4 v = make_float4(0.f, 0.f, 0.f, 0.f);
        if (n < NUM_NODES) {
            const float* src = (n < NUM_USER) ? (pref + (size_t)n * DIM_LATENT)
                                              : (feat + (size_t)(n - NUM_USER) * DIM_LATENT);
            v = reinterpret_cast<const float4*>(src)[lane];
        }
        float ss = v.x*v.x + v.y*v.y + v.z*v.z + v.w*v.w;
        #pragma unroll
        for (int off = 32; off >= 1; off >>= 1) ss += __shfl_xor(ss, off);
        float sc = 1.0f / fmaxf(sqrtf(ss), 1e-12f);
        ushort4 p;
        p.x = f2bf(v.x * sc); p.y = f2bf(v.y * sc);
        p.z = f2bf(v.z * sc); p.w = f2bf(v.w * sc);
        *reinterpret_cast<ushort4*>(&xs[w * 16 + r][lane * 4]) = p;
    }
    __syncthreads();

    f4_t acc[8];
    #pragma unroll
    for (int t = 0; t < 8; ++t) acc[t] = (f4_t){0.f, 0.f, 0.f, 0.f};

    const bf8_t* wf = reinterpret_cast<const bf8_t*>(wfrag);
    #pragma unroll 2
    for (int ks = 0; ks < 8; ++ks) {
        bf8_t a = *reinterpret_cast<const bf8_t*>(&xs[w * 16 + ql][ks * 32 + q * 8]);
        #pragma unroll
        for (int t = 0; t < 8; ++t) {
            bf8_t b = wf[(ks * 8 + t) * 64 + lane];
            acc[t] = __builtin_amdgcn_mfma_f32_16x16x32_bf16(a, b, acc[t], 0, 0, 0);
        }
    }

    int nn[4];
    float dn[4];
    #pragma unroll
    for (int reg = 0; reg < 4; ++reg) {
        nn[reg] = rowBase + w * 16 + q * 4 + reg;
        dn[reg] = (nn[reg] < NUM_NODES) ? dis[nn[reg]] : 0.0f;
    }
    #pragma unroll
    for (int t = 0; t < 4; ++t) {
        int colg = t * 16 + ql;
        #pragma unroll
        for (int reg = 0; reg < 4; ++reg)
            if (nn[reg] < NUM_NODES)
                hbf[(size_t)nn[reg] * DIM_ID + colg] = f2bf(acc[t][reg] * dn[reg]);
    }
    #pragma unroll
    for (int t = 4; t < 8; ++t) {
        int colg = (t - 4) * 16 + ql;
        float lbl = lb[colg];
        #pragma unroll
        for (int reg = 0; reg < 4; ++reg)
            if (nn[reg] < NUM_NODES) {
                size_t o = (size_t)nn[reg] * DIM_ID + colg;
                xhat[o] = f2bf(lrelu(acc[t][reg] + lbl) + idemb[o]);
            }
    }
}

// ---------------- aggregate: H[n] = dis[n] * sum_{e: row=n} hbf[col[e]] ----------------
// one block per 256-node bucket; 64KB LDS accumulator; lane = dim
__global__ void __launch_bounds__(512) k_agg(
    const unsigned short* __restrict__ hbf, const float* __restrict__ dis,
    const uint2* __restrict__ epair, const int* __restrict__ boff,
    float* __restrict__ H)
{
    __shared__ float Hs[256 * DIM_ID];   // 64 KB
    const int t = threadIdx.x;
    const int lane = t & 63, w = t >> 6;
    const int b = blockIdx.x;
    const int nodeBase = b << 8;

    #pragma unroll
    for (int i = 0; i < 8; ++i)
        reinterpret_cast<float4*>(Hs)[t + i * 512] = make_float4(0.f, 0.f, 0.f, 0.f);
    __syncthreads();

    const int start = boff[b], end = boff[b + 1];
    for (int e0 = start + w * 4; e0 < end; e0 += 32) {
        uint2 p[4];
        #pragma unroll
        for (int i = 0; i < 4; ++i)
            p[i] = (e0 + i < end) ? epair[e0 + i] : make_uint2(0u, 0xffffffffu);
        float v[4];
        #pragma unroll
        for (int i = 0; i < 4; ++i)
            if (p[i].y != 0xffffffffu)
                v[i] = bf2f(hbf[(size_t)p[i].y * DIM_ID + lane]);
        #pragma unroll
        for (int i = 0; i < 4; ++i)
            if (p[i].y != 0xffffffffu)
                atomicAdd(&Hs[(int)((p[i].x & 255u) << 6) + lane], v[i]);
    }
    __syncthreads();

    #pragma unroll
    for (int k = 0; k < 8; ++k) {
        int i4 = t + k * 512;            // float4 index, 4096 total
        int r = i4 >> 4;
        int n = nodeBase + r;
        if (n < NUM_NODES) {
            float dn = dis[n];
            float4 hv = reinterpret_cast<const float4*>(Hs)[i4];
            hv.x *= dn; hv.y *= dn; hv.z *= dn; hv.w *= dn;
            reinterpret_cast<float4*>(H)[(size_t)n * 16 + (i4 & 15)] = hv;
        }
    }
}

// ---------------- mid: x1 = lrelu(lrelu(H)@gw0+gb0+xhat1);
//                  hbf = bf16(dis*(x1@Wg1)); xhat2 = bf16(lrelu(x1@lw1+b1)+id) ----------------
__global__ void __launch_bounds__(256) k_mid(
    const float* __restrict__ H, const unsigned short* __restrict__ xhat1,
    const float* __restrict__ gw, const float* __restrict__ gb,
    const float* __restrict__ Wg1, const float* __restrict__ lw1,
    const float* __restrict__ lb1, const float* __restrict__ idemb,
    const float* __restrict__ dis,
    unsigned short* __restrict__ hbf, unsigned short* __restrict__ xhat2)
{
    __shared__ float hs[32][DIM_ID];
    __shared__ float x1[32][DIM_ID];
    const int t = threadIdx.x;
    const int w = t >> 6;
    const int lane = t & 63;
    const int rowBase = blockIdx.x * 32;
    const int lrb = w * 8;

    for (int i = t; i < 32 * DIM_ID; i += 256) {
        int r = i >> 6, d = i & 63;
        hs[r][d] = lrelu(H[(size_t)(rowBase + r) * DIM_ID + d]);
    }
    __syncthreads();

    {
        float acc[8] = {0,0,0,0,0,0,0,0};
        for (int k = 0; k < DIM_ID; k += 4) {
            float g0 = gw[(k+0)*DIM_ID + lane];
            float g1 = gw[(k+1)*DIM_ID + lane];
            float g2 = gw[(k+2)*DIM_ID + lane];
            float g3 = gw[(k+3)*DIM_ID + lane];
            #pragma unroll
            for (int r = 0; r < 8; ++r) {
                float4 hv = *reinterpret_cast<const float4*>(&hs[lrb + r][k]);
                acc[r] += hv.x*g0 + hv.y*g1 + hv.z*g2 + hv.w*g3;
            }
        }
        float gbl = gb[lane];
        #pragma unroll
        for (int r = 0; r < 8; ++r) {
            size_t n = rowBase + lrb + r;
            x1[lrb + r][lane] = lrelu(acc[r] + gbl + bf2f(xhat1[n * DIM_ID + lane]));
        }
    }
    __syncthreads();

    float a0[8] = {0,0,0,0,0,0,0,0};
    float a1[8] = {0,0,0,0,0,0,0,0};
    for (int k = 0; k < DIM_ID; k += 4) {
        float wg0 = Wg1[(k+0)*DIM_ID + lane];
        float wg1 = Wg1[(k+1)*DIM_ID + lane];
        float wg2 = Wg1[(k+2)*DIM_ID + lane];
        float wg3 = Wg1[(k+3)*DIM_ID + lane];
        float wl0 = lw1[(k+0)*DIM_ID + lane];
        float wl1 = lw1[(k+1)*DIM_ID + lane];
        float wl2 = lw1[(k+2)*DIM_ID + lane];
        float wl3 = lw1[(k+3)*DIM_ID + lane];
        #pragma unroll
        for (int r = 0; r < 8; ++r) {
            float4 x4 = *reinterpret_cast<const float4*>(&x1[lrb + r][k]);
            a0[r] += x4.x*wg0 + x4.y*wg1 + x4.z*wg2 + x4.w*wg3;
            a1[r] += x4.x*wl0 + x4.y*wl1 + x4.z*wl2 + x4.w*wl3;
        }
    }
    float lbl = lb1[lane];
    #pragma unroll
    for (int r = 0; r < 8; ++r) {
        size_t n = rowBase + lrb + r;
        float dn = dis[n];
        hbf[n * DIM_ID + lane] = f2bf(a0[r] * dn);
        xhat2[n * DIM_ID + lane] = f2bf(lrelu(a1[r] + lbl) + idemb[n * DIM_ID + lane]);
    }
}

// ---------------- final: out = lrelu(lrelu(H2)@gw1 + gb1 + xhat2) ----------------
__global__ void __launch_bounds__(256) k_final(
    const float* __restrict__ H, const unsigned short* __restrict__ xhat,
    const float* __restrict__ gw, const float* __restrict__ gb,
    float* __restrict__ out)
{
    __shared__ float hs[32][DIM_ID];
    const int t = threadIdx.x;
    const int w = t >> 6;
    const int lane = t & 63;
    const int rowBase = blockIdx.x * 32;
    const int lrb = w * 8;

    for (int i = t; i < 32 * DIM_ID; i += 256) {
        int r = i >> 6, d = i & 63;
        hs[r][d] = lrelu(H[(size_t)(rowBase + r) * DIM_ID + d]);
    }
    __syncthreads();

    float acc[8] = {0,0,0,0,0,0,0,0};
    for (int k = 0; k < DIM_ID; k += 4) {
        float g0 = gw[(k+0)*DIM_ID + lane];
        float g1 = gw[(k+1)*DIM_ID + lane];
        float g2 = gw[(k+2)*DIM_ID + lane];
        float g3 = gw[(k+3)*DIM_ID + lane];
        #pragma unroll
        for (int r = 0; r < 8; ++r) {
            float4 hv = *reinterpret_cast<const float4*>(&hs[lrb + r][k]);
            acc[r] += hv.x*g0 + hv.y*g1 + hv.z*g2 + hv.w*g3;
        }
    }
    float gbl = gb[lane];
    #pragma unroll
    for (int r = 0; r < 8; ++r) {
        size_t n = rowBase + lrb + r;
        out[n * DIM_ID + lane] = lrelu(acc[r] + gbl + bf2f(xhat[n * DIM_ID + lane]));
    }
}

extern "C" void kernel_launch(void* const* d_in, const int* in_sizes, int n_in,
                              void* d_out, int out_size, void* d_ws, size_t ws_size,
                              hipStream_t stream)
{
    const float* features = (const float*)d_in[0];
    const float* idemb    = (const float*)d_in[1];
    const float* pref     = (const float*)d_in[2];
    const float* Wg0      = (const float*)d_in[3];
    const float* Wg1      = (const float*)d_in[4];
    const float* lw0      = (const float*)d_in[5];
    const float* lb0      = (const float*)d_in[6];
    const float* lw1      = (const float*)d_in[7];
    const float* lb1      = (const float*)d_in[8];
    const float* gw0      = (const float*)d_in[9];
    const float* gb0      = (const float*)d_in[10];
    const float* gw1      = (const float*)d_in[11];
    const float* gb1      = (const float*)d_in[12];
    const int*   edges    = (const int*)d_in[13];
    const int*   row      = edges;
    const int*   col      = edges + NUM_EDGES;

    char* ws = (char*)d_ws;
    int*   cnt     = (int*)(ws + 0);            // 400000 B (pad 524288)
    int*   bcnt    = (int*)(ws + 524288);       // 4 KB
    int*   boff    = (int*)(ws + 528384);       // 4 KB
    int*   bcursor = (int*)(ws + 532480);       // 4 KB
    float* dis     = (float*)(ws + 536576);     // 400000 B (pad 524288)
    uint2* epair   = (uint2*)(ws + 1060864);    // 16 MB
    unsigned short* wfrag = (unsigned short*)(ws + 17838080);  // 64 KB
    unsigned short* hbf   = (unsigned short*)(ws + 17903616);  // 12.8 MB
    unsigned short* xhatb = (unsigned short*)(ws + 30703616);  // 12.8 MB
    float* Hbuf  = (float*)(ws + 43503616);                    // 25.6 MB -> 69.1 MB total
    float* out   = (float*)d_out;

    const int edgeBlocks = (NUM_EDGES + 255) / 256;
    const int l1Blocks = (NUM_NODES + 63) / 64;     // 1563
    const int rowBlocks32 = NUM_NODES / 32;         // 3125

    // ---- prep ----
    hipMemsetAsync(cnt, 0, NUM_NODES * sizeof(int), stream);
    k_wprep<<<16, 256, 0, stream>>>(Wg0, lw0, wfrag);
    k_count<<<edgeBlocks, 256, 0, stream>>>(row, cnt);
    k_bcnt<<<NBUCKET, 256, 0, stream>>>(cnt, bcnt, dis);
    k_bscan<<<1, 512, 0, stream>>>(bcnt, boff, bcursor);
    k_bin<<<edgeBlocks, 256, 0, stream>>>(row, col, bcursor, epair);

    // ---- layer 1 ----
    k_l1<<<l1Blocks, 256, 0, stream>>>(pref, features, wfrag, lb0, idemb, dis,
                                       hbf, xhatb);
    k_agg<<<NBUCKET, 512, 0, stream>>>(hbf, dis, epair, boff, Hbuf);

    // ---- combine1 + layer2 pre (fused) ----
    k_mid<<<rowBlocks32, 256, 0, stream>>>(Hbuf, xhatb, gw0, gb0, Wg1, lw1, lb1,
                                           idemb, dis, hbf, xhatb);

    // ---- layer 2 aggregate + final combine ----
    k_agg<<<NBUCKET, 512, 0, stream>>>(hbf, dis, epair, boff, Hbuf);
    k_final<<<rowBlocks32, 256, 0, stream>>>(Hbuf, xhatb, gw1, gb1, out);
}

// Round 5
// 311.998 us; speedup vs baseline: 8.6609x; 8.6609x over previous
//
#include <hip/hip_runtime.h>

#define NUM_USER   50000
#define NUM_ITEM   50000
#define NUM_NODES  100000
#define DIM_LATENT 256
#define DIM_ID     64
#define NUM_EDGES  2000000
#define NBUCKET    391        // ceil(100000/256) buckets of 256 nodes
#define BPB        8192       // edges per chunk for counting sort
#define NCHUNK     245        // ceil(NUM_EDGES/BPB)
#define HSTRIDE    392

typedef __attribute__((ext_vector_type(8))) short bf8_t;
typedef __attribute__((ext_vector_type(4))) float f4_t;

static __device__ __forceinline__ float lrelu(float x) {
    return x > 0.0f ? x : 0.01f * x;
}
static __device__ __forceinline__ unsigned short f2bf(float f) {
    unsigned u = __float_as_uint(f);
    u += 0x7fff + ((u >> 16) & 1);
    return (unsigned short)(u >> 16);
}
static __device__ __forceinline__ float bf2f(unsigned short u) {
    return __uint_as_float(((unsigned)u) << 16);
}

// ---------------- pass 1: per-chunk bucket histogram (LDS atomics only) ----------------
__global__ void __launch_bounds__(256) k_hist(const int* __restrict__ row,
                                              int* __restrict__ hist) {
    __shared__ int lh[NBUCKET];
    const int g = blockIdx.x, t = threadIdx.x;
    for (int i = t; i < NBUCKET; i += 256) lh[i] = 0;
    __syncthreads();
    const int base = g * BPB;
    for (int i = 0; i < BPB; i += 256) {
        int e = base + i + t;
        if (e < NUM_EDGES) atomicAdd(&lh[row[e] >> 8], 1);
    }
    __syncthreads();
    for (int i = t; i < NBUCKET; i += 256) hist[g * HSTRIDE + i] = lh[i];
}

// ---------------- pass 2a: per-bucket scan over chunks; hist -> exclusive, bcnt ----------------
__global__ void __launch_bounds__(256) k_off1(int* __restrict__ hist,
                                              int* __restrict__ bcnt) {
    __shared__ int wsum[4];
    const int b = blockIdx.x, t = threadIdx.x;
    const int lane = t & 63, w = t >> 6;
    int c = (t < NCHUNK) ? hist[t * HSTRIDE + b] : 0;
    int v = c;
    #pragma unroll
    for (int off = 1; off < 64; off <<= 1) {
        int u = __shfl_up(v, off);
        if (lane >= off) v += u;
    }
    if (lane == 63) wsum[w] = v;
    __syncthreads();
    int add = 0;
    #pragma unroll
    for (int i = 0; i < 4; ++i) if (i < w) add += wsum[i];
    int incl = v + add;
    if (t < NCHUNK) hist[t * HSTRIDE + b] = incl - c;
    if (t == 255) bcnt[b] = incl;
}

// ---------------- pass 2b: exclusive scan over 391 bucket counts -> boff ----------------
__global__ void __launch_bounds__(512) k_bscan(const int* __restrict__ bcnt,
                                               int* __restrict__ boff) {
    __shared__ int wsum[8];
    const int t = threadIdx.x;
    const int lane = t & 63, w = t >> 6;
    int c = (t < NBUCKET) ? bcnt[t] : 0;
    int v = c;
    #pragma unroll
    for (int off = 1; off < 64; off <<= 1) {
        int u = __shfl_up(v, off);
        if (lane >= off) v += u;
    }
    if (lane == 63) wsum[w] = v;
    __syncthreads();
    int add = 0;
    #pragma unroll
    for (int i = 0; i < 8; ++i) if (i < w) add += wsum[i];
    int ex = v + add - c;
    if (t < NBUCKET) boff[t] = ex;
    if (t == NBUCKET - 1) boff[NBUCKET] = ex + c;   // == NUM_EDGES
}

// ---------------- pass 3: scatter edges to bucket-contiguous epair via LDS cursors ----------------
__global__ void __launch_bounds__(256) k_bin2(const int* __restrict__ row,
                                              const int* __restrict__ col,
                                              const int* __restrict__ hist,
                                              const int* __restrict__ boff,
                                              uint2* __restrict__ epair) {
    __shared__ int curs[NBUCKET];
    const int g = blockIdx.x, t = threadIdx.x;
    for (int i = t; i < NBUCKET; i += 256) curs[i] = boff[i] + hist[g * HSTRIDE + i];
    __syncthreads();
    const int base = g * BPB;
    for (int i = 0; i < BPB; i += 256) {
        int e = base + i + t;
        if (e < NUM_EDGES) {
            int r = row[e];
            int pos = atomicAdd(&curs[r >> 8], 1);
            epair[pos] = make_uint2((unsigned)r, (unsigned)col[e]);
        }
    }
}

// ---------------- pass 4: bucket-local exact CSR: offs, cnt, dis, ecol ----------------
__global__ void __launch_bounds__(512) k_csr(const uint2* __restrict__ epair,
                                             const int* __restrict__ boff,
                                             int* __restrict__ offs,
                                             int* __restrict__ cnt,
                                             float* __restrict__ dis,
                                             int* __restrict__ ecol) {
    __shared__ int lcnt[256];
    __shared__ int lofs[256];
    __shared__ int wsum[4];
    const int b = blockIdx.x, t = threadIdx.x;
    const int start = boff[b], end = boff[b + 1];
    if (t < 256) lcnt[t] = 0;
    __syncthreads();
    for (int e = start + t; e < end; e += 512)
        atomicAdd(&lcnt[epair[e].x & 255u], 1);
    __syncthreads();

    const int lane = t & 63, w = t >> 6;
    int c = (t < 256) ? lcnt[t] : 0;
    int v = c;
    #pragma unroll
    for (int off = 1; off < 64; off <<= 1) {
        int u = __shfl_up(v, off);
        if (lane >= off) v += u;
    }
    if (t < 256 && lane == 63) wsum[w] = v;
    __syncthreads();
    if (t < 256) {
        int add = 0;
        #pragma unroll
        for (int i = 0; i < 4; ++i) if (i < w) add += wsum[i];
        int ex = v + add - c;
        lofs[t] = start + ex;
        int n = (b << 8) + t;
        if (n < NUM_NODES) {
            offs[n] = start + ex;
            cnt[n]  = c;
            dis[n]  = rsqrtf((float)max(c, 1));
        }
    }
    __syncthreads();
    for (int e = start + t; e < end; e += 512) {
        uint2 p = epair[e];
        int pos = atomicAdd(&lofs[p.x & 255u], 1);
        ecol[pos] = (int)p.y;
    }
}

// ---------------- weight prep: Wg0,lw0 -> bf16 fragment-order table ----------------
__global__ void __launch_bounds__(256) k_wprep(const float* __restrict__ Wg,
                                               const float* __restrict__ Wl,
                                               unsigned short* __restrict__ wfrag) {
    int g = blockIdx.x * 256 + threadIdx.x;     // 4096 total
    if (g >= 4096) return;
    int ks = g >> 9;
    int t  = (g >> 6) & 7;
    int l  = g & 63;
    const float* W = (t < 4) ? Wg : Wl;
    int colg = (t & 3) * 16 + (l & 15);
    int kb = ks * 32 + (l >> 4) * 8;
    unsigned short o[8];
    #pragma unroll
    for (int e = 0; e < 8; ++e) o[e] = f2bf(W[(size_t)(kb + e) * DIM_ID + colg]);
    unsigned short* dst = wfrag + (size_t)g * 8;
    #pragma unroll
    for (int e = 0; e < 8; ++e) dst[e] = o[e];
}

// ---------------- layer 1 (MFMA) ----------------
__global__ void __launch_bounds__(256) k_l1(
    const float* __restrict__ pref, const float* __restrict__ feat,
    const unsigned short* __restrict__ wfrag,
    const float* __restrict__ lb,   const float* __restrict__ idemb,
    const float* __restrict__ dis,
    unsigned short* __restrict__ hbf, unsigned short* __restrict__ xhat)
{
    __shared__ unsigned short xs[64][264];
    const int w = threadIdx.x >> 6;
    const int lane = threadIdx.x & 63;
    const int ql = lane & 15, q = lane >> 4;
    const int rowBase = blockIdx.x * 64;

    for (int r = 0; r < 16; ++r) {
        int n = rowBase + w * 16 + r;
        float4 v = make_float4(0.f, 0.f, 0.f, 0.f);
        if (n < NUM_NODES) {
            const float* src = (n < NUM_USER) ? (pref + (size_t)n * DIM_LATENT)
                                              : (feat + (size_t)(n - NUM_USER) * DIM_LATENT);
            v = reinterpret_cast<const float4*>(src)[lane];
        }
        float ss = v.x*v.x + v.y*v.y + v.z*v.z + v.w*v.w;
        #pragma unroll
        for (int off = 32; off >= 1; off >>= 1) ss += __shfl_xor(ss, off);
        float sc = 1.0f / fmaxf(sqrtf(ss), 1e-12f);
        ushort4 p;
        p.x = f2bf(v.x * sc); p.y = f2bf(v.y * sc);
        p.z = f2bf(v.z * sc); p.w = f2bf(v.w * sc);
        *reinterpret_cast<ushort4*>(&xs[w * 16 + r][lane * 4]) = p;
    }
    __syncthreads();

    f4_t acc[8];
    #pragma unroll
    for (int t = 0; t < 8; ++t) acc[t] = (f4_t){0.f, 0.f, 0.f, 0.f};

    const bf8_t* wf = reinterpret_cast<const bf8_t*>(wfrag);
    #pragma unroll 2
    for (int ks = 0; ks < 8; ++ks) {
        bf8_t a = *reinterpret_cast<const bf8_t*>(&xs[w * 16 + ql][ks * 32 + q * 8]);
        #pragma unroll
        for (int t = 0; t < 8; ++t) {
            bf8_t b = wf[(ks * 8 + t) * 64 + lane];
            acc[t] = __builtin_amdgcn_mfma_f32_16x16x32_bf16(a, b, acc[t], 0, 0, 0);
        }
    }

    int nn[4];
    float dn[4];
    #pragma unroll
    for (int reg = 0; reg < 4; ++reg) {
        nn[reg] = rowBase + w * 16 + q * 4 + reg;
        dn[reg] = (nn[reg] < NUM_NODES) ? dis[nn[reg]] : 0.0f;
    }
    #pragma unroll
    for (int t = 0; t < 4; ++t) {
        int colg = t * 16 + ql;
        #pragma unroll
        for (int reg = 0; reg < 4; ++reg)
            if (nn[reg] < NUM_NODES)
                hbf[(size_t)nn[reg] * DIM_ID + colg] = f2bf(acc[t][reg] * dn[reg]);
    }
    #pragma unroll
    for (int t = 4; t < 8; ++t) {
        int colg = (t - 4) * 16 + ql;
        float lbl = lb[colg];
        #pragma unroll
        for (int reg = 0; reg < 4; ++reg)
            if (nn[reg] < NUM_NODES) {
                size_t o = (size_t)nn[reg] * DIM_ID + colg;
                xhat[o] = f2bf(lrelu(acc[t][reg] + lbl) + idemb[o]);
            }
    }
}

// ---------------- gather: H[n] = dis[n] * sum_e hbf[ecol[e]]  (hbf pre-scaled) ----------------
// one wave per node; quarter-wave per edge; 8 gathered loads in flight
__global__ void __launch_bounds__(256) k_gather(
    const unsigned short* __restrict__ hbf, const float* __restrict__ dis,
    const int* __restrict__ offs, const int* __restrict__ cnt,
    const int* __restrict__ ecol, float* __restrict__ H)
{
    const int w = threadIdx.x >> 6;
    const int lane = threadIdx.x & 63;
    const int ql = lane & 15, q = lane >> 4;
    const int n = blockIdx.x * 4 + w;

    int start = offs[n];
    int m = cnt[n];
    float a0 = 0.f, a1 = 0.f, a2 = 0.f, a3 = 0.f;

    for (int base = 0; base < m; base += 64) {
        int e = base + lane;
        int ec = (e < m) ? ecol[start + e] : 0;
        int lim = m - base; if (lim > 64) lim = 64;
        int nj = (lim + 3) >> 2;
        int j = 0;
        for (; j + 2 <= nj; j += 2) {
            int i0 = j * 4 + q;
            int i1 = i0 + 4;
            int c0 = __shfl(ec, i0);
            int c1 = __shfl(ec, i1);
            uint2 u0 = make_uint2(0u, 0u), u1 = make_uint2(0u, 0u);
            if (i0 < lim) u0 = *reinterpret_cast<const uint2*>(&hbf[(size_t)c0 * DIM_ID + ql * 4]);
            if (i1 < lim) u1 = *reinterpret_cast<const uint2*>(&hbf[(size_t)c1 * DIM_ID + ql * 4]);
            a0 += __uint_as_float(u0.x << 16) + __uint_as_float(u1.x << 16);
            a1 += __uint_as_float(u0.x & 0xffff0000u) + __uint_as_float(u1.x & 0xffff0000u);
            a2 += __uint_as_float(u0.y << 16) + __uint_as_float(u1.y << 16);
            a3 += __uint_as_float(u0.y & 0xffff0000u) + __uint_as_float(u1.y & 0xffff0000u);
        }
        if (j < nj) {
            int i0 = j * 4 + q;
            int c0 = __shfl(ec, i0);
            if (i0 < lim) {
                uint2 u = *reinterpret_cast<const uint2*>(&hbf[(size_t)c0 * DIM_ID + ql * 4]);
                a0 += __uint_as_float(u.x << 16);
                a1 += __uint_as_float(u.x & 0xffff0000u);
                a2 += __uint_as_float(u.y << 16);
                a3 += __uint_as_float(u.y & 0xffff0000u);
            }
        }
    }
    #pragma unroll
    for (int off = 16; off <= 32; off <<= 1) {
        a0 += __shfl_xor(a0, off);
        a1 += __shfl_xor(a1, off);
        a2 += __shfl_xor(a2, off);
        a3 += __shfl_xor(a3, off);
    }
    if (lane < 16) {
        float dn = dis[n];
        float4 o = make_float4(a0 * dn, a1 * dn, a2 * dn, a3 * dn);
        *reinterpret_cast<float4*>(&H[(size_t)n * DIM_ID + lane * 4]) = o;
    }
}

// ---------------- mid: x1 = lrelu(lrelu(H)@gw0+gb0+xhat1);
//                  hbf = bf16(dis*(x1@Wg1)); xhat2 = bf16(lrelu(x1@lw1+b1)+id) ----------------
__global__ void __launch_bounds__(256) k_mid(
    const float* __restrict__ H, const unsigned short* __restrict__ xhat1,
    const float* __restrict__ gw, const float* __restrict__ gb,
    const float* __restrict__ Wg1, const float* __restrict__ lw1,
    const float* __restrict__ lb1, const float* __restrict__ idemb,
    const float* __restrict__ dis,
    unsigned short* __restrict__ hbf, unsigned short* __restrict__ xhat2)
{
    __shared__ float hs[32][DIM_ID];
    __shared__ float x1[32][DIM_ID];
    const int t = threadIdx.x;
    const int w = t >> 6;
    const int lane = t & 63;
    const int rowBase = blockIdx.x * 32;
    const int lrb = w * 8;

    for (int i = t; i < 32 * DIM_ID; i += 256) {
        int r = i >> 6, d = i & 63;
        hs[r][d] = lrelu(H[(size_t)(rowBase + r) * DIM_ID + d]);
    }
    __syncthreads();

    {
        float acc[8] = {0,0,0,0,0,0,0,0};
        for (int k = 0; k < DIM_ID; k += 4) {
            float g0 = gw[(k+0)*DIM_ID + lane];
            float g1 = gw[(k+1)*DIM_ID + lane];
            float g2 = gw[(k+2)*DIM_ID + lane];
            float g3 = gw[(k+3)*DIM_ID + lane];
            #pragma unroll
            for (int r = 0; r < 8; ++r) {
                float4 hv = *reinterpret_cast<const float4*>(&hs[lrb + r][k]);
                acc[r] += hv.x*g0 + hv.y*g1 + hv.z*g2 + hv.w*g3;
            }
        }
        float gbl = gb[lane];
        #pragma unroll
        for (int r = 0; r < 8; ++r) {
            size_t n = rowBase + lrb + r;
            x1[lrb + r][lane] = lrelu(acc[r] + gbl + bf2f(xhat1[n * DIM_ID + lane]));
        }
    }
    __syncthreads();

    float a0[8] = {0,0,0,0,0,0,0,0};
    float a1[8] = {0,0,0,0,0,0,0,0};
    for (int k = 0; k < DIM_ID; k += 4) {
        float wg0 = Wg1[(k+0)*DIM_ID + lane];
        float wg1 = Wg1[(k+1)*DIM_ID + lane];
        float wg2 = Wg1[(k+2)*DIM_ID + lane];
        float wg3 = Wg1[(k+3)*DIM_ID + lane];
        float wl0 = lw1[(k+0)*DIM_ID + lane];
        float wl1 = lw1[(k+1)*DIM_ID + lane];
        float wl2 = lw1[(k+2)*DIM_ID + lane];
        float wl3 = lw1[(k+3)*DIM_ID + lane];
        #pragma unroll
        for (int r = 0; r < 8; ++r) {
            float4 x4 = *reinterpret_cast<const float4*>(&x1[lrb + r][k]);
            a0[r] += x4.x*wg0 + x4.y*wg1 + x4.z*wg2 + x4.w*wg3;
            a1[r] += x4.x*wl0 + x4.y*wl1 + x4.z*wl2 + x4.w*wl3;
        }
    }
    float lbl = lb1[lane];
    #pragma unroll
    for (int r = 0; r < 8; ++r) {
        size_t n = rowBase + lrb + r;
        float dn = dis[n];
        hbf[n * DIM_ID + lane] = f2bf(a0[r] * dn);
        xhat2[n * DIM_ID + lane] = f2bf(lrelu(a1[r] + lbl) + idemb[n * DIM_ID + lane]);
    }
}

// ---------------- final: out = lrelu(lrelu(H2)@gw1 + gb1 + xhat2) ----------------
__global__ void __launch_bounds__(256) k_final(
    const float* __restrict__ H, const unsigned short* __restrict__ xhat,
    const float* __restrict__ gw, const float* __restrict__ gb,
    float* __restrict__ out)
{
    __shared__ float hs[32][DIM_ID];
    const int t = threadIdx.x;
    const int w = t >> 6;
    const int lane = t & 63;
    const int rowBase = blockIdx.x * 32;
    const int lrb = w * 8;

    for (int i = t; i < 32 * DIM_ID; i += 256) {
        int r = i >> 6, d = i & 63;
        hs[r][d] = lrelu(H[(size_t)(rowBase + r) * DIM_ID + d]);
    }
    __syncthreads();

    float acc[8] = {0,0,0,0,0,0,0,0};
    for (int k = 0; k < DIM_ID; k += 4) {
        float g0 = gw[(k+0)*DIM_ID + lane];
        float g1 = gw[(k+1)*DIM_ID + lane];
        float g2 = gw[(k+2)*DIM_ID + lane];
        float g3 = gw[(k+3)*DIM_ID + lane];
        #pragma unroll
        for (int r = 0; r < 8; ++r) {
            float4 hv = *reinterpret_cast<const float4*>(&hs[lrb + r][k]);
            acc[r] += hv.x*g0 + hv.y*g1 + hv.z*g2 + hv.w*g3;
        }
    }
    float gbl = gb[lane];
    #pragma unroll
    for (int r = 0; r < 8; ++r) {
        size_t n = rowBase + lrb + r;
        out[n * DIM_ID + lane] = lrelu(acc[r] + gbl + bf2f(xhat[n * DIM_ID + lane]));
    }
}

extern "C" void kernel_launch(void* const* d_in, const int* in_sizes, int n_in,
                              void* d_out, int out_size, void* d_ws, size_t ws_size,
                              hipStream_t stream)
{
    const float* features = (const float*)d_in[0];
    const float* idemb    = (const float*)d_in[1];
    const float* pref     = (const float*)d_in[2];
    const float* Wg0      = (const float*)d_in[3];
    const float* Wg1      = (const float*)d_in[4];
    const float* lw0      = (const float*)d_in[5];
    const float* lb0      = (const float*)d_in[6];
    const float* lw1      = (const float*)d_in[7];
    const float* lb1      = (const float*)d_in[8];
    const float* gw0      = (const float*)d_in[9];
    const float* gb0      = (const float*)d_in[10];
    const float* gw1      = (const float*)d_in[11];
    const float* gb1      = (const float*)d_in[12];
    const int*   edges    = (const int*)d_in[13];
    const int*   row      = edges;
    const int*   col      = edges + NUM_EDGES;

    char* ws = (char*)d_ws;
    int*   hist  = (int*)(ws + 0);              // 245*392*4 = 384,160 B (pad 512K)
    int*   bcnt  = (int*)(ws + 524288);         // 4 KB
    int*   boff  = (int*)(ws + 528384);         // 4 KB (392 ints)
    int*   offs  = (int*)(ws + 532480);         // 400 KB (pad 512K)
    int*   cnt   = (int*)(ws + 1056768);        // 400 KB (pad 512K)
    float* dis   = (float*)(ws + 1581056);      // 400 KB (pad 512K)
    int*   ecol  = (int*)(ws + 2105344);        // 8 MB
    uint2* epair = (uint2*)(ws + 10493952);     // 16 MB
    unsigned short* wfrag = (unsigned short*)(ws + 27271168);  // 64 KB
    unsigned short* hbf   = (unsigned short*)(ws + 27336704);  // 12.8 MB
    unsigned short* xhatb = (unsigned short*)(ws + 40136704);  // 12.8 MB
    float* Hbuf  = (float*)(ws + 52936704);                    // 25.6 MB -> 78.5 MB total
    float* out   = (float*)d_out;

    const int l1Blocks = (NUM_NODES + 63) / 64;     // 1563
    const int rowBlocks32 = NUM_NODES / 32;         // 3125
    const int gatherBlocks = NUM_NODES / 4;         // 25000

    // ---- CSR build (3-pass counting sort + bucket-local exact CSR) ----
    k_wprep<<<16, 256, 0, stream>>>(Wg0, lw0, wfrag);
    k_hist<<<NCHUNK, 256, 0, stream>>>(row, hist);
    k_off1<<<NBUCKET, 256, 0, stream>>>(hist, bcnt);
    k_bscan<<<1, 512, 0, stream>>>(bcnt, boff);
    k_bin2<<<NCHUNK, 256, 0, stream>>>(row, col, hist, boff, epair);
    k_csr<<<NBUCKET, 512, 0, stream>>>(epair, boff, offs, cnt, dis, ecol);

    // ---- layer 1 ----
    k_l1<<<l1Blocks, 256, 0, stream>>>(pref, features, wfrag, lb0, idemb, dis,
                                       hbf, xhatb);
    k_gather<<<gatherBlocks, 256, 0, stream>>>(hbf, dis, offs, cnt, ecol, Hbuf);

    // ---- combine1 + layer2 pre (fused) ----
    k_mid<<<rowBlocks32, 256, 0, stream>>>(Hbuf, xhatb, gw0, gb0, Wg1, lw1, lb1,
                                           idemb, dis, hbf, xhatb);

    // ---- layer 2 aggregate + final combine ----
    k_gather<<<gatherBlocks, 256, 0, stream>>>(hbf, dis, offs, cnt, ecol, Hbuf);
    k_final<<<rowBlocks32, 256, 0, stream>>>(Hbuf, xhatb, gw1, gb1, out);
}

// Round 6
// 290.571 us; speedup vs baseline: 9.2995x; 1.0737x over previous
//
#include <hip/hip_runtime.h>

#define NUM_USER   50000
#define NUM_ITEM   50000
#define NUM_NODES  100000
#define DIM_LATENT 256
#define DIM_ID     64
#define NUM_EDGES  2000000
#define NBUCKET    391        // ceil(100000/256) buckets of 256 nodes
#define BPB        8192       // edges per chunk for counting sort
#define NCHUNK     245        // ceil(NUM_EDGES/BPB)
#define HSTRIDE    392

typedef __attribute__((ext_vector_type(8))) short bf8_t;
typedef __attribute__((ext_vector_type(4))) float f4_t;

static __device__ __forceinline__ float lrelu(float x) {
    return x > 0.0f ? x : 0.01f * x;
}
static __device__ __forceinline__ unsigned short f2bf(float f) {
    unsigned u = __float_as_uint(f);
    u += 0x7fff + ((u >> 16) & 1);
    return (unsigned short)(u >> 16);
}
static __device__ __forceinline__ float bf2f(unsigned short u) {
    return __uint_as_float(((unsigned)u) << 16);
}
static __device__ __forceinline__ float bflo(unsigned u) {
    return __uint_as_float(u << 16);
}
static __device__ __forceinline__ float bfhi(unsigned u) {
    return __uint_as_float(u & 0xffff0000u);
}

// ---------------- pass 1: per-chunk bucket histogram (LDS atomics only) ----------------
__global__ void __launch_bounds__(256) k_hist(const int* __restrict__ row,
                                              int* __restrict__ hist) {
    __shared__ int lh[NBUCKET];
    const int g = blockIdx.x, t = threadIdx.x;
    for (int i = t; i < NBUCKET; i += 256) lh[i] = 0;
    __syncthreads();
    const int base = g * BPB;
    for (int i = 0; i < BPB; i += 256) {
        int e = base + i + t;
        if (e < NUM_EDGES) atomicAdd(&lh[row[e] >> 8], 1);
    }
    __syncthreads();
    for (int i = t; i < NBUCKET; i += 256) hist[g * HSTRIDE + i] = lh[i];
}

// ---------------- pass 2a: per-bucket scan over chunks; hist -> exclusive, bcnt ----------------
__global__ void __launch_bounds__(256) k_off1(int* __restrict__ hist,
                                              int* __restrict__ bcnt) {
    __shared__ int wsum[4];
    const int b = blockIdx.x, t = threadIdx.x;
    const int lane = t & 63, w = t >> 6;
    int c = (t < NCHUNK) ? hist[t * HSTRIDE + b] : 0;
    int v = c;
    #pragma unroll
    for (int off = 1; off < 64; off <<= 1) {
        int u = __shfl_up(v, off);
        if (lane >= off) v += u;
    }
    if (lane == 63) wsum[w] = v;
    __syncthreads();
    int add = 0;
    #pragma unroll
    for (int i = 0; i < 4; ++i) if (i < w) add += wsum[i];
    int incl = v + add;
    if (t < NCHUNK) hist[t * HSTRIDE + b] = incl - c;
    if (t == 255) bcnt[b] = incl;
}

// ---------------- pass 2b: exclusive scan over 391 bucket counts -> boff ----------------
__global__ void __launch_bounds__(512) k_bscan(const int* __restrict__ bcnt,
                                               int* __restrict__ boff) {
    __shared__ int wsum[8];
    const int t = threadIdx.x;
    const int lane = t & 63, w = t >> 6;
    int c = (t < NBUCKET) ? bcnt[t] : 0;
    int v = c;
    #pragma unroll
    for (int off = 1; off < 64; off <<= 1) {
        int u = __shfl_up(v, off);
        if (lane >= off) v += u;
    }
    if (lane == 63) wsum[w] = v;
    __syncthreads();
    int add = 0;
    #pragma unroll
    for (int i = 0; i < 8; ++i) if (i < w) add += wsum[i];
    int ex = v + add - c;
    if (t < NBUCKET) boff[t] = ex;
    if (t == NBUCKET - 1) boff[NBUCKET] = ex + c;   // == NUM_EDGES
}

// ---------------- pass 3: scatter packed edges to bucket-contiguous epack ----------------
// pack: (local_node << 24) | col   (col < 2^17)
__global__ void __launch_bounds__(256) k_bin2(const int* __restrict__ row,
                                              const int* __restrict__ col,
                                              const int* __restrict__ hist,
                                              const int* __restrict__ boff,
                                              unsigned* __restrict__ epack) {
    __shared__ int curs[NBUCKET];
    const int g = blockIdx.x, t = threadIdx.x;
    for (int i = t; i < NBUCKET; i += 256) curs[i] = boff[i] + hist[g * HSTRIDE + i];
    __syncthreads();
    const int base = g * BPB;
    for (int i = 0; i < BPB; i += 256) {
        int e = base + i + t;
        if (e < NUM_EDGES) {
            int r = row[e];
            int pos = atomicAdd(&curs[r >> 8], 1);
            epack[pos] = ((unsigned)(r & 255) << 24) | (unsigned)col[e];
        }
    }
}

// ---------------- pass 4: bucket-local exact CSR: offs, cnt, dis, ecol ----------------
__global__ void __launch_bounds__(512) k_csr(const unsigned* __restrict__ epack,
                                             const int* __restrict__ boff,
                                             int* __restrict__ offs,
                                             int* __restrict__ cnt,
                                             float* __restrict__ dis,
                                             int* __restrict__ ecol) {
    __shared__ int lcnt[256];
    __shared__ int lofs[256];
    __shared__ int wsum[4];
    const int b = blockIdx.x, t = threadIdx.x;
    const int start = boff[b], end = boff[b + 1];
    if (t < 256) lcnt[t] = 0;
    __syncthreads();
    for (int e = start + t; e < end; e += 512)
        atomicAdd(&lcnt[epack[e] >> 24], 1);
    __syncthreads();

    const int lane = t & 63, w = t >> 6;
    int c = (t < 256) ? lcnt[t] : 0;
    int v = c;
    #pragma unroll
    for (int off = 1; off < 64; off <<= 1) {
        int u = __shfl_up(v, off);
        if (lane >= off) v += u;
    }
    if (t < 256 && lane == 63) wsum[w] = v;
    __syncthreads();
    if (t < 256) {
        int add = 0;
        #pragma unroll
        for (int i = 0; i < 4; ++i) if (i < w) add += wsum[i];
        int ex = v + add - c;
        lofs[t] = start + ex;
        int n = (b << 8) + t;
        if (n < NUM_NODES) {
            offs[n] = start + ex;
            cnt[n]  = c;
            dis[n]  = rsqrtf((float)max(c, 1));
        }
    }
    __syncthreads();
    for (int e = start + t; e < end; e += 512) {
        unsigned p = epack[e];
        int pos = atomicAdd(&lofs[p >> 24], 1);
        ecol[pos] = (int)(p & 0x00ffffffu);
    }
}

// ---------------- weight prep: Wg0,lw0 -> bf16 fragment-order table ----------------
__global__ void __launch_bounds__(256) k_wprep(const float* __restrict__ Wg,
                                               const float* __restrict__ Wl,
                                               unsigned short* __restrict__ wfrag) {
    int g = blockIdx.x * 256 + threadIdx.x;     // 4096 total
    if (g >= 4096) return;
    int ks = g >> 9;
    int t  = (g >> 6) & 7;
    int l  = g & 63;
    const float* W = (t < 4) ? Wg : Wl;
    int colg = (t & 3) * 16 + (l & 15);
    int kb = ks * 32 + (l >> 4) * 8;
    unsigned short o[8];
    #pragma unroll
    for (int e = 0; e < 8; ++e) o[e] = f2bf(W[(size_t)(kb + e) * DIM_ID + colg]);
    unsigned short* dst = wfrag + (size_t)g * 8;
    #pragma unroll
    for (int e = 0; e < 8; ++e) dst[e] = o[e];
}

// ---------------- layer 1 (MFMA): batched-ILP normalize + GEMM ----------------
__global__ void __launch_bounds__(256) k_l1(
    const float* __restrict__ pref, const float* __restrict__ feat,
    const unsigned short* __restrict__ wfrag,
    const float* __restrict__ lb,   const float* __restrict__ idemb,
    const float* __restrict__ dis,
    unsigned short* __restrict__ hbf, unsigned short* __restrict__ xhat)
{
    __shared__ unsigned short xs[64][264];
    const int w = threadIdx.x >> 6;
    const int lane = threadIdx.x & 63;
    const int ql = lane & 15, q = lane >> 4;
    const int rowBase = blockIdx.x * 64;

    // phase 1: normalize 16 rows/wave in two batches of 8 (8 loads in flight)
    #pragma unroll
    for (int half = 0; half < 2; ++half) {
        float4 v[8];
        #pragma unroll
        for (int r = 0; r < 8; ++r) {
            int n = rowBase + w * 16 + half * 8 + r;
            v[r] = make_float4(0.f, 0.f, 0.f, 0.f);
            if (n < NUM_NODES) {
                const float* src = (n < NUM_USER) ? (pref + (size_t)n * DIM_LATENT)
                                                  : (feat + (size_t)(n - NUM_USER) * DIM_LATENT);
                v[r] = reinterpret_cast<const float4*>(src)[lane];
            }
        }
        #pragma unroll
        for (int r = 0; r < 8; ++r) {
            float ss = v[r].x*v[r].x + v[r].y*v[r].y + v[r].z*v[r].z + v[r].w*v[r].w;
            #pragma unroll
            for (int off = 32; off >= 1; off >>= 1) ss += __shfl_xor(ss, off);
            float sc = 1.0f / fmaxf(sqrtf(ss), 1e-12f);
            ushort4 p;
            p.x = f2bf(v[r].x * sc); p.y = f2bf(v[r].y * sc);
            p.z = f2bf(v[r].z * sc); p.w = f2bf(v[r].w * sc);
            *reinterpret_cast<ushort4*>(&xs[w * 16 + half * 8 + r][lane * 4]) = p;
        }
    }
    __syncthreads();

    // phase 2: 8 K-steps x 8 N-tiles of mfma 16x16x32
    f4_t acc[8];
    #pragma unroll
    for (int t = 0; t < 8; ++t) acc[t] = (f4_t){0.f, 0.f, 0.f, 0.f};

    const bf8_t* wf = reinterpret_cast<const bf8_t*>(wfrag);
    #pragma unroll 2
    for (int ks = 0; ks < 8; ++ks) {
        bf8_t a = *reinterpret_cast<const bf8_t*>(&xs[w * 16 + ql][ks * 32 + q * 8]);
        #pragma unroll
        for (int t = 0; t < 8; ++t) {
            bf8_t b = wf[(ks * 8 + t) * 64 + lane];
            acc[t] = __builtin_amdgcn_mfma_f32_16x16x32_bf16(a, b, acc[t], 0, 0, 0);
        }
    }

    int nn[4];
    float dn[4];
    #pragma unroll
    for (int reg = 0; reg < 4; ++reg) {
        nn[reg] = rowBase + w * 16 + q * 4 + reg;
        dn[reg] = (nn[reg] < NUM_NODES) ? dis[nn[reg]] : 0.0f;
    }
    #pragma unroll
    for (int t = 0; t < 4; ++t) {
        int colg = t * 16 + ql;
        #pragma unroll
        for (int reg = 0; reg < 4; ++reg)
            if (nn[reg] < NUM_NODES)
                hbf[(size_t)nn[reg] * DIM_ID + colg] = f2bf(acc[t][reg] * dn[reg]);
    }
    #pragma unroll
    for (int t = 4; t < 8; ++t) {
        int colg = (t - 4) * 16 + ql;
        float lbl = lb[colg];
        #pragma unroll
        for (int reg = 0; reg < 4; ++reg)
            if (nn[reg] < NUM_NODES) {
                size_t o = (size_t)nn[reg] * DIM_ID + colg;
                xhat[o] = f2bf(lrelu(acc[t][reg] + lbl) + idemb[o]);
            }
    }
}

// ---------------- gather: Hb[n] = bf16(dis[n] * sum_e hbf[ecol[e]]) ----------------
// one wave per node; eighth-wave per edge (uint4 = 8 bf16 per lane); 16 edges in flight
__global__ void __launch_bounds__(256) k_gather(
    const unsigned short* __restrict__ hbf, const float* __restrict__ dis,
    const int* __restrict__ offs, const int* __restrict__ cnt,
    const int* __restrict__ ecol, unsigned short* __restrict__ Hb)
{
    const int w = threadIdx.x >> 6;
    const int lane = threadIdx.x & 63;
    const int g = lane >> 3;      // edge slot 0..7
    const int k = lane & 7;       // dim octet 0..7
    const int n = blockIdx.x * 4 + w;

    int start = offs[n];
    int m = cnt[n];
    float a0=0.f,a1=0.f,a2=0.f,a3=0.f,a4=0.f,a5=0.f,a6=0.f,a7=0.f;

    for (int base = 0; base < m; base += 64) {
        int e = base + lane;
        int ec = (e < m) ? ecol[start + e] : 0;
        int lim = m - base; if (lim > 64) lim = 64;
        int nj = (lim + 7) >> 3;
        int j = 0;
        for (; j + 2 <= nj; j += 2) {
            int i0 = j * 8 + g, i1 = i0 + 8;
            int c0 = __shfl(ec, i0);
            int c1 = __shfl(ec, i1);
            uint4 u0 = make_uint4(0u,0u,0u,0u), u1 = make_uint4(0u,0u,0u,0u);
            if (i0 < lim) u0 = *reinterpret_cast<const uint4*>(&hbf[(size_t)c0 * DIM_ID + k * 8]);
            if (i1 < lim) u1 = *reinterpret_cast<const uint4*>(&hbf[(size_t)c1 * DIM_ID + k * 8]);
            a0 += bflo(u0.x) + bflo(u1.x);  a1 += bfhi(u0.x) + bfhi(u1.x);
            a2 += bflo(u0.y) + bflo(u1.y);  a3 += bfhi(u0.y) + bfhi(u1.y);
            a4 += bflo(u0.z) + bflo(u1.z);  a5 += bfhi(u0.z) + bfhi(u1.z);
            a6 += bflo(u0.w) + bflo(u1.w);  a7 += bfhi(u0.w) + bfhi(u1.w);
        }
        if (j < nj) {
            int i0 = j * 8 + g;
            int c0 = __shfl(ec, i0);
            if (i0 < lim) {
                uint4 u = *reinterpret_cast<const uint4*>(&hbf[(size_t)c0 * DIM_ID + k * 8]);
                a0 += bflo(u.x); a1 += bfhi(u.x);
                a2 += bflo(u.y); a3 += bfhi(u.y);
                a4 += bflo(u.z); a5 += bfhi(u.z);
                a6 += bflo(u.w); a7 += bfhi(u.w);
            }
        }
    }
    #pragma unroll
    for (int off = 8; off <= 32; off <<= 1) {
        a0 += __shfl_xor(a0, off); a1 += __shfl_xor(a1, off);
        a2 += __shfl_xor(a2, off); a3 += __shfl_xor(a3, off);
        a4 += __shfl_xor(a4, off); a5 += __shfl_xor(a5, off);
        a6 += __shfl_xor(a6, off); a7 += __shfl_xor(a7, off);
    }
    if (lane < 8) {
        float dn = dis[n];
        uint4 o;
        o.x = (unsigned)f2bf(a0 * dn) | ((unsigned)f2bf(a1 * dn) << 16);
        o.y = (unsigned)f2bf(a2 * dn) | ((unsigned)f2bf(a3 * dn) << 16);
        o.z = (unsigned)f2bf(a4 * dn) | ((unsigned)f2bf(a5 * dn) << 16);
        o.w = (unsigned)f2bf(a6 * dn) | ((unsigned)f2bf(a7 * dn) << 16);
        *reinterpret_cast<uint4*>(&Hb[(size_t)n * DIM_ID + lane * 8]) = o;
    }
}

// ---------------- mid: x1 = lrelu(lrelu(H)@gw0+gb0+xhat1);
//                  hbf = bf16(dis*(x1@Wg1)); xhat2 = bf16(lrelu(x1@lw1+b1)+id) ----------------
__global__ void __launch_bounds__(256) k_mid(
    const unsigned short* __restrict__ Hb, const unsigned short* __restrict__ xhat1,
    const float* __restrict__ gw, const float* __restrict__ gb,
    const float* __restrict__ Wg1, const float* __restrict__ lw1,
    const float* __restrict__ lb1, const float* __restrict__ idemb,
    const float* __restrict__ dis,
    unsigned short* __restrict__ hbf, unsigned short* __restrict__ xhat2)
{
    __shared__ float hs[32][DIM_ID];
    __shared__ float x1[32][DIM_ID];
    const int t = threadIdx.x;
    const int w = t >> 6;
    const int lane = t & 63;
    const int rowBase = blockIdx.x * 32;
    const int lrb = w * 8;

    const unsigned* Hu = reinterpret_cast<const unsigned*>(Hb + (size_t)rowBase * DIM_ID);
    #pragma unroll
    for (int iu = 0; iu < 1024; iu += 256) {
        unsigned u = Hu[iu + t];
        int r = (iu + t) >> 5;
        int d = ((iu + t) & 31) * 2;
        hs[r][d]     = lrelu(bflo(u));
        hs[r][d + 1] = lrelu(bfhi(u));
    }
    __syncthreads();

    {
        float acc[8] = {0,0,0,0,0,0,0,0};
        for (int k = 0; k < DIM_ID; k += 4) {
            float g0 = gw[(k+0)*DIM_ID + lane];
            float g1 = gw[(k+1)*DIM_ID + lane];
            float g2 = gw[(k+2)*DIM_ID + lane];
            float g3 = gw[(k+3)*DIM_ID + lane];
            #pragma unroll
            for (int r = 0; r < 8; ++r) {
                float4 hv = *reinterpret_cast<const float4*>(&hs[lrb + r][k]);
                acc[r] += hv.x*g0 + hv.y*g1 + hv.z*g2 + hv.w*g3;
            }
        }
        float gbl = gb[lane];
        #pragma unroll
        for (int r = 0; r < 8; ++r) {
            size_t n = rowBase + lrb + r;
            x1[lrb + r][lane] = lrelu(acc[r] + gbl + bf2f(xhat1[n * DIM_ID + lane]));
        }
    }
    __syncthreads();

    float a0[8] = {0,0,0,0,0,0,0,0};
    float a1[8] = {0,0,0,0,0,0,0,0};
    for (int k = 0; k < DIM_ID; k += 4) {
        float wg0 = Wg1[(k+0)*DIM_ID + lane];
        float wg1 = Wg1[(k+1)*DIM_ID + lane];
        float wg2 = Wg1[(k+2)*DIM_ID + lane];
        float wg3 = Wg1[(k+3)*DIM_ID + lane];
        float wl0 = lw1[(k+0)*DIM_ID + lane];
        float wl1 = lw1[(k+1)*DIM_ID + lane];
        float wl2 = lw1[(k+2)*DIM_ID + lane];
        float wl3 = lw1[(k+3)*DIM_ID + lane];
        #pragma unroll
        for (int r = 0; r < 8; ++r) {
            float4 x4 = *reinterpret_cast<const float4*>(&x1[lrb + r][k]);
            a0[r] += x4.x*wg0 + x4.y*wg1 + x4.z*wg2 + x4.w*wg3;
            a1[r] += x4.x*wl0 + x4.y*wl1 + x4.z*wl2 + x4.w*wl3;
        }
    }
    float lbl = lb1[lane];
    #pragma unroll
    for (int r = 0; r < 8; ++r) {
        size_t n = rowBase + lrb + r;
        float dn = dis[n];
        hbf[n * DIM_ID + lane] = f2bf(a0[r] * dn);
        xhat2[n * DIM_ID + lane] = f2bf(lrelu(a1[r] + lbl) + idemb[n * DIM_ID + lane]);
    }
}

// ---------------- final: out = lrelu(lrelu(H2)@gw1 + gb1 + xhat2) ----------------
__global__ void __launch_bounds__(256) k_final(
    const unsigned short* __restrict__ Hb, const unsigned short* __restrict__ xhat,
    const float* __restrict__ gw, const float* __restrict__ gb,
    float* __restrict__ out)
{
    __shared__ float hs[32][DIM_ID];
    const int t = threadIdx.x;
    const int w = t >> 6;
    const int lane = t & 63;
    const int rowBase = blockIdx.x * 32;
    const int lrb = w * 8;

    const unsigned* Hu = reinterpret_cast<const unsigned*>(Hb + (size_t)rowBase * DIM_ID);
    #pragma unroll
    for (int iu = 0; iu < 1024; iu += 256) {
        unsigned u = Hu[iu + t];
        int r = (iu + t) >> 5;
        int d = ((iu + t) & 31) * 2;
        hs[r][d]     = lrelu(bflo(u));
        hs[r][d + 1] = lrelu(bfhi(u));
    }
    __syncthreads();

    float acc[8] = {0,0,0,0,0,0,0,0};
    for (int k = 0; k < DIM_ID; k += 4) {
        float g0 = gw[(k+0)*DIM_ID + lane];
        float g1 = gw[(k+1)*DIM_ID + lane];
        float g2 = gw[(k+2)*DIM_ID + lane];
        float g3 = gw[(k+3)*DIM_ID + lane];
        #pragma unroll
        for (int r = 0; r < 8; ++r) {
            float4 hv = *reinterpret_cast<const float4*>(&hs[lrb + r][k]);
            acc[r] += hv.x*g0 + hv.y*g1 + hv.z*g2 + hv.w*g3;
        }
    }
    float gbl = gb[lane];
    #pragma unroll
    for (int r = 0; r < 8; ++r) {
        size_t n = rowBase + lrb + r;
        out[n * DIM_ID + lane] = lrelu(acc[r] + gbl + bf2f(xhat[n * DIM_ID + lane]));
    }
}

extern "C" void kernel_launch(void* const* d_in, const int* in_sizes, int n_in,
                              void* d_out, int out_size, void* d_ws, size_t ws_size,
                              hipStream_t stream)
{
    const float* features = (const float*)d_in[0];
    const float* idemb    = (const float*)d_in[1];
    const float* pref     = (const float*)d_in[2];
    const float* Wg0      = (const float*)d_in[3];
    const float* Wg1      = (const float*)d_in[4];
    const float* lw0      = (const float*)d_in[5];
    const float* lb0      = (const float*)d_in[6];
    const float* lw1      = (const float*)d_in[7];
    const float* lb1      = (const float*)d_in[8];
    const float* gw0      = (const float*)d_in[9];
    const float* gb0      = (const float*)d_in[10];
    const float* gw1      = (const float*)d_in[11];
    const float* gb1      = (const float*)d_in[12];
    const int*   edges    = (const int*)d_in[13];
    const int*   row      = edges;
    const int*   col      = edges + NUM_EDGES;

    char* ws = (char*)d_ws;
    int*      hist  = (int*)(ws + 0);             // 384,160 B (pad 512K)
    int*      bcnt  = (int*)(ws + 524288);        // 4 KB
    int*      boff  = (int*)(ws + 528384);        // 4 KB
    int*      offs  = (int*)(ws + 532480);        // 400 KB (pad 512K)
    int*      cnt   = (int*)(ws + 1056768);       // 400 KB (pad 512K)
    float*    dis   = (float*)(ws + 1581056);     // 400 KB (pad 512K)
    int*      ecol  = (int*)(ws + 2105344);       // 8 MB
    unsigned* epack = (unsigned*)(ws + 10493952); // 8 MB
    unsigned short* wfrag = (unsigned short*)(ws + 18882560);  // 64 KB
    unsigned short* hbf   = (unsigned short*)(ws + 18948096);  // 12.8 MB
    unsigned short* xhatb = (unsigned short*)(ws + 31748096);  // 12.8 MB
    unsigned short* Hbf   = (unsigned short*)(ws + 44548096);  // 12.8 MB -> 57.3 MB total
    float* out   = (float*)d_out;

    const int l1Blocks = (NUM_NODES + 63) / 64;     // 1563
    const int rowBlocks32 = NUM_NODES / 32;         // 3125
    const int gatherBlocks = NUM_NODES / 4;         // 25000

    // ---- CSR build (3-pass counting sort + bucket-local exact CSR) ----
    k_wprep<<<16, 256, 0, stream>>>(Wg0, lw0, wfrag);
    k_hist<<<NCHUNK, 256, 0, stream>>>(row, hist);
    k_off1<<<NBUCKET, 256, 0, stream>>>(hist, bcnt);
    k_bscan<<<1, 512, 0, stream>>>(bcnt, boff);
    k_bin2<<<NCHUNK, 256, 0, stream>>>(row, col, hist, boff, epack);
    k_csr<<<NBUCKET, 512, 0, stream>>>(epack, boff, offs, cnt, dis, ecol);

    // ---- layer 1 ----
    k_l1<<<l1Blocks, 256, 0, stream>>>(pref, features, wfrag, lb0, idemb, dis,
                                       hbf, xhatb);
    k_gather<<<gatherBlocks, 256, 0, stream>>>(hbf, dis, offs, cnt, ecol, Hbf);

    // ---- combine1 + layer2 pre (fused) ----
    k_mid<<<rowBlocks32, 256, 0, stream>>>(Hbf, xhatb, gw0, gb0, Wg1, lw1, lb1,
                                           idemb, dis, hbf, xhatb);

    // ---- layer 2 aggregate + final combine ----
    k_gather<<<gatherBlocks, 256, 0, stream>>>(hbf, dis, offs, cnt, ecol, Hbf);
    k_final<<<rowBlocks32, 256, 0, stream>>>(Hbf, xhatb, gw1, gb1, out);
}